// Round 3
// baseline (95.002 us; speedup 1.0000x reference)
//
#include <hip/hip_runtime.h>

// OPU via MFMA. R18 = R17 presplit (unchanged) + opu_main restructured from 4-wave
// k-split to per-wave 32x32 OUTPUT QUADRANTS over full K.
// Why: k-split made every wave quant-accumulate all 4096 tile outputs -> 4096 adds/wave
// (~16.4K cyc/SIMD, > MFMA pipe time) + 4-barrier wave-serial LDS combine + 512 loads/
// wave with 1-chunk lookahead (~230cyc cover vs 200-400cyc L2 latency -> stall-bound).
// Quadrant split: 1024 adds/wave (4x less), NO combine/barriers/cb-LDS, 256 loads/wave,
// 4-uint4 chunk buffer -> 3-deep prefetch (12 loads in flight) within 128-VGPR cap.
// Cost: block-aggregate L2 traffic 2x (each A/B half read by 2 waves) = 512MB total,
// far below L2 ceiling; L1 catches intra-block duplicates.
// R17 carried: biased-magic quant (res at 1.5*2^23; fp32 RNE in `res += acc` IS the
// per-chunk ADC rint; |swing|<=1120 << 4.19M margin), W-presplit folded into 512
// X-blocks (one balanced pass), merged-plane layout (4KB page/chunk), table-driven
// presplit (bit-identical), AlBl dropped (|err|<=4e-6), clip provably dead, per-XCD
// swizzle. R16 post-mortem: hipLaunchCooperativeKernel never executed under graph
// capture (absmax == max|ref| => all-zero out); coop launch banned.

typedef unsigned int u32;
typedef unsigned short u16;
typedef _Float16 f16x8 __attribute__((ext_vector_type(8)));
typedef float f32x16 __attribute__((ext_vector_type(16)));

#define M_TOT 2048
#define N_TOT 1024
#define K_TOT 1024
#define RBIAS 12582912.0f  // 1.5 * 2^23: fp32 ulp = 1.0, integer-grid RNE in the add

__device__ __forceinline__ u32 split_pack(float a) {
  _Float16 h = (_Float16)a;              // v_cvt_f16_f32 (RNE)
  _Float16 l = (_Float16)(a - (float)h); // exact fp32 sub then RNE
  return (u32)__builtin_bit_cast(u16, h) | ((u32)__builtin_bit_cast(u16, l) << 16);
}
__device__ __forceinline__ u32 pk_lo(u32 a, u32 b) { return (a & 0xffffu) | (b << 16); }
__device__ __forceinline__ u32 pk_hi(u32 a, u32 b) { return (a >> 16) | (b & 0xffff0000u); }

__global__ __launch_bounds__(256) void presplit(
    const float* __restrict__ x, const float* __restrict__ w,
    const float* __restrict__ vl, const float* __restrict__ wl,
    u16* __restrict__ XHL, u16* __restrict__ WHL)
{
  __shared__ __align__(16) char lds[16384];  // X 4-chunk plane image
  __shared__ u32 tabX[256];
  __shared__ u32 tabW[256];

  const int b   = blockIdx.x;   // 512 blocks: each does one X tile-group AND one W slice
  const int tid = threadIdx.x;

  // ---- split tables: a = fl(x + vlut) (X) and fl(fl(w + wlut) * 1/16) (W) ----
  {
    const int j = tid >> 4, xi = tid & 15;
    const float base = (float)(xi - 8);
    tabX[tid] = split_pack(base + vl[j * 16 + xi]);
    tabW[tid] = split_pack((base + wl[j * 16 + xi]) * 0.0625f);
  }
  __syncthreads();

  // ---- W presplit: thread = one (ch, oct, n) item; 512*256 == 128*1024 exactly ----
  {
    const int g2 = b * 256 + tid;
    const int n  = g2 & 1023;
    const int co = g2 >> 10;                // 0..127 = (ch, oct)
    const int ch = co >> 1, oct = co & 1;
    const int nblk = n >> 6, ng = (n >> 5) & 1, n32 = n & 31;
    const float* wp = w + (size_t)(ch * 16 + oct * 8) * N_TOT + n;

    u32 hp[4], lp[4];
#pragma unroll
    for (int e2 = 0; e2 < 4; ++e2) {
      const int e = e2 * 2;
      const float w0 = wp[(size_t)e * N_TOT];
      const float w1 = wp[(size_t)(e + 1) * N_TOT];
      const u32 t0 = tabW[(oct * 8 + e) * 16 + (int)(w0 + 8.0f)];
      const u32 t1 = tabW[(oct * 8 + e + 1) * 16 + (int)(w1 + 8.0f)];
      hp[e2] = pk_lo(t0, t1);
      lp[e2] = pk_hi(t0, t1);
    }
    // chunk base (u16): (nblk*64+ch)*2048 ; layout hl*1024 + ng*512 + oct*256 + n32*8
    const size_t wb = (size_t)(nblk * 64 + ch) * 2048 + ng * 512 + oct * 256 + n32 * 8;
    *(uint4*)&WHL[wb]        = make_uint4(hp[0], hp[1], hp[2], hp[3]);
    *(uint4*)&WHL[wb + 1024] = make_uint4(lp[0], lp[1], lp[2], lp[3]);
  }

  // ---- X presplit: block = (mblk, chunk-group of 4) ----
  {
    const int mblk = b >> 4, chg = b & 15;
    const int ml = tid >> 2, chl = tid & 3;
    const int rg = ml >> 5, row = ml & 31;
    const float4* xp4 = (const float4*)(x + (size_t)(mblk * 64 + ml) * K_TOT + (chg * 4 + chl) * 16);
    float4 v4[4] = { xp4[0], xp4[1], xp4[2], xp4[3] };
    const float* v = (const float*)v4;

    u32 hp[8], lp[8];
#pragma unroll
    for (int e2 = 0; e2 < 8; ++e2) {
      const int e = e2 * 2;
      const u32 t0 = tabX[e * 16 + (int)(v[e] + 8.0f)];
      const u32 t1 = tabX[(e + 1) * 16 + (int)(v[e + 1] + 8.0f)];
      hp[e2] = pk_lo(t0, t1);
      lp[e2] = pk_hi(t0, t1);
    }

    // LDS image in exact global layout: chl*4096 + hl*2048 + rg*1024 + oct*512 + row*16
    char* basep = lds + chl * 4096 + rg * 1024 + row * 16;
    *(uint4*)(basep)        = make_uint4(hp[0], hp[1], hp[2], hp[3]);  // h oct0
    *(uint4*)(basep + 512)  = make_uint4(hp[4], hp[5], hp[6], hp[7]);  // h oct1
    *(uint4*)(basep + 2048) = make_uint4(lp[0], lp[1], lp[2], lp[3]);  // l oct0
    *(uint4*)(basep + 2560) = make_uint4(lp[4], lp[5], lp[6], lp[7]);  // l oct1
    __syncthreads();

    // coalesced dump: 16KB contiguous (4 chunk-planes)
    const size_t gb = (size_t)(mblk * 64 + chg * 4) * 4096;  // bytes
    const int off = tid * 16;
    *(uint4*)((char*)XHL + gb + off)         = *(const uint4*)(lds + off);
    *(uint4*)((char*)XHL + gb + off + 4096)  = *(const uint4*)(lds + off + 4096);
    *(uint4*)((char*)XHL + gb + off + 8192)  = *(const uint4*)(lds + off + 8192);
    *(uint4*)((char*)XHL + gb + off + 12288) = *(const uint4*)(lds + off + 12288);
  }
}

__global__ __launch_bounds__(256, 2) void opu_main(
    const u16* __restrict__ XHL, const u16* __restrict__ WHL,
    float* __restrict__ out)
{
  const int tid  = threadIdx.x;
  const int wave = tid >> 6;
  const int lane = tid & 63;
  const int oct  = lane >> 5;
  const int ll   = lane & 31;
  const int mt   = wave >> 1;     // A row-group (rg) owned by this wave
  const int nt   = wave & 1;      // B col-group (ng) owned by this wave

  const int bx   = blockIdx.x;
  const int nblk = (bx & 1) + 2 * ((bx >> 3) & 7);   // 0..15  per-XCD swizzle
  const int mblk = ((bx >> 1) & 3) + 4 * (bx >> 6);  // 0..31

  // chunk stride 2048 u16 (4KB page: [hl][rg|ng][oct][32][k8]); wave reads only its
  // (mt / nt) half of each page: 2 x b128 from A + 2 x b128 from B per chunk.
  const u16* pA = XHL + (size_t)mblk * 131072 + mt * 512 + lane * 8;
  const u16* pB = WHL + (size_t)nblk * 131072 + nt * 512 + lane * 8;

  uint4 c0[4], c1[4], c2[4], c3[4];  // literal-indexed only (R7 lesson)

#define LQ(dst, ch)                                        \
  do {                                                     \
    const size_t o = (size_t)(ch) * 2048;                  \
    (dst)[0] = *(const uint4*)(pA + o);                    \
    (dst)[1] = *(const uint4*)(pA + o + 1024);             \
    (dst)[2] = *(const uint4*)(pB + o);                    \
    (dst)[3] = *(const uint4*)(pB + o + 1024);             \
  } while (0)

  float res[16];
#pragma unroll
  for (int i = 0; i < 16; ++i) res[i] = RBIAS;  // biased: each add RNE-rounds to int grid
  const f32x16 fzero = {};

  // Per chunk: 3-MFMA chain (AlBl dropped) then biased res += acc = per-chunk ADC rint.
#define CQ(c)                                                                     \
  do {                                                                            \
    const f16x8 Ah = __builtin_bit_cast(f16x8, (c)[0]);                           \
    const f16x8 Al = __builtin_bit_cast(f16x8, (c)[1]);                           \
    const f16x8 Bh = __builtin_bit_cast(f16x8, (c)[2]);                           \
    const f16x8 Bl = __builtin_bit_cast(f16x8, (c)[3]);                           \
    f32x16 a = __builtin_amdgcn_mfma_f32_32x32x16_f16(Ah, Bh, fzero, 0, 0, 0);    \
    a = __builtin_amdgcn_mfma_f32_32x32x16_f16(Al, Bh, a, 0, 0, 0);               \
    a = __builtin_amdgcn_mfma_f32_32x32x16_f16(Ah, Bl, a, 0, 0, 0);               \
    _Pragma("unroll")                                                             \
    for (int i = 0; i < 16; ++i) res[i] += a[i];                                  \
  } while (0)

#define CLAMP63(v) ((v) > 63 ? 63 : (v))

  LQ(c0, 0); LQ(c1, 1); LQ(c2, 2);
#pragma unroll 1
  for (int it = 0; it < 16; ++it) {
    const int ch = it * 4;
    LQ(c3, ch + 3);            CQ(c0);
    LQ(c0, CLAMP63(ch + 4));   CQ(c1);   // tail iterations redundantly reload ch 63
    LQ(c1, CLAMP63(ch + 5));   CQ(c2);
    LQ(c2, CLAMP63(ch + 6));   CQ(c3);
  }

  // ---- direct per-wave store: 32x32 C/D layout col=ll, row=(i&3)+8*(i>>2)+4*oct ----
  float* op = out + (size_t)(mblk * 64 + mt * 32 + 4 * oct) * N_TOT + nblk * 64 + nt * 32 + ll;
#pragma unroll
  for (int i = 0; i < 16; ++i) {
    const int r = (i & 3) + 8 * (i >> 2);
    op[(size_t)r * N_TOT] = (res[i] - RBIAS) * 16.0f;
  }
}

extern "C" void kernel_launch(void* const* d_in, const int* in_sizes, int n_in,
                              void* d_out, int out_size, void* d_ws, size_t ws_size,
                              hipStream_t stream)
{
  const float* input  = (const float*)d_in[0];
  const float* weight = (const float*)d_in[1];
  const float* vmap   = (const float*)d_in[2];
  const float* wmap   = (const float*)d_in[3];
  float* out = (float*)d_out;

  u16* XHL = (u16*)d_ws;                         // 8MB (4M u16)
  u16* WHL = XHL + 4 * 1024 * 1024;              // 4MB   (ws use: 12MB total)

  presplit<<<512, 256, 0, stream>>>(input, weight, vmap, wmap, XHL, WHL);

  opu_main<<<512, 256, 0, stream>>>(XHL, WHL, out);
}

// Round 4
// 90.645 us; speedup vs baseline: 1.0481x; 1.0481x over previous
//
#include <hip/hip_runtime.h>

// OPU via MFMA. R19 = R17 presplit (unchanged) + main rebuilt: 512-thread blocks,
// wave = (k-half x quadrant), 3-deep prefetch, 2-step combine.
// R18 post-mortem (95us, +9): quadrant-only split saved NO quant VALU (R17 was already
// 1024 adds/wave, my 4096 claim was a miscount) while doubling per-lane load traffic
// and serializing MFMA chains -> pure loss. Also: R18 total +9 with no kernel >46.9us
// in top-5 proves dur_us INCLUDES the ~45us harness workspace-poison fill; controllable
// budget is only ~41us (presplit ~12 + gap ~4 + main ~25).
// R19 theory: main is latency-bound at 2 waves/SIMD (grid 512 x 256thr is grid-limited
// occupancy; issue floor ~8us vs observed ~25). 512-thr blocks (8 waves: kh 0/1 x
// quadrant mt,nt) double TLP to 4 waves/SIMD with UNCHANGED unique per-block traffic
// (A 256KB + B 256KB; intra-block duplicate half-page reads are L1-temporal), VGPR
// ~105 < 128 cap, 4-buffer literal rotation = 3-chunk-deep prefetch (12 loads in
// flight), combine 4 barrier steps -> 2 (kh0 writes cb, kh1 adds).
// Numerics unchanged: per-chunk biased-RNE rint (res at 1.5*2^23), 64 rints/output
// summed exactly (32 in-reg per kh + exact LDS add); AlBl dropped (|err|<=4e-6);
// clip provably dead. R16 lesson: hipLaunchCooperativeKernel never executes under
// graph capture -> banned. Carried: merged-plane 4KB/chunk pages, table-driven
// presplit (bit-identical), W folded into 512 X-blocks, per-XCD swizzle.

typedef unsigned int u32;
typedef unsigned short u16;
typedef _Float16 f16x8 __attribute__((ext_vector_type(8)));
typedef float f32x16 __attribute__((ext_vector_type(16)));

#define M_TOT 2048
#define N_TOT 1024
#define K_TOT 1024
#define RBIAS 12582912.0f  // 1.5 * 2^23: fp32 ulp = 1.0, integer-grid RNE in the add

__device__ __forceinline__ u32 split_pack(float a) {
  _Float16 h = (_Float16)a;              // v_cvt_f16_f32 (RNE)
  _Float16 l = (_Float16)(a - (float)h); // exact fp32 sub then RNE
  return (u32)__builtin_bit_cast(u16, h) | ((u32)__builtin_bit_cast(u16, l) << 16);
}
__device__ __forceinline__ u32 pk_lo(u32 a, u32 b) { return (a & 0xffffu) | (b << 16); }
__device__ __forceinline__ u32 pk_hi(u32 a, u32 b) { return (a >> 16) | (b & 0xffff0000u); }

__global__ __launch_bounds__(256) void presplit(
    const float* __restrict__ x, const float* __restrict__ w,
    const float* __restrict__ vl, const float* __restrict__ wl,
    u16* __restrict__ XHL, u16* __restrict__ WHL)
{
  __shared__ __align__(16) char lds[16384];  // X 4-chunk plane image
  __shared__ u32 tabX[256];
  __shared__ u32 tabW[256];

  const int b   = blockIdx.x;   // 512 blocks: each does one X tile-group AND one W slice
  const int tid = threadIdx.x;

  // ---- split tables: a = fl(x + vlut) (X) and fl(fl(w + wlut) * 1/16) (W) ----
  {
    const int j = tid >> 4, xi = tid & 15;
    const float base = (float)(xi - 8);
    tabX[tid] = split_pack(base + vl[j * 16 + xi]);
    tabW[tid] = split_pack((base + wl[j * 16 + xi]) * 0.0625f);
  }
  __syncthreads();

  // ---- W presplit: thread = one (ch, oct, n) item; 512*256 == 128*1024 exactly ----
  {
    const int g2 = b * 256 + tid;
    const int n  = g2 & 1023;
    const int co = g2 >> 10;                // 0..127 = (ch, oct)
    const int ch = co >> 1, oct = co & 1;
    const int nblk = n >> 6, ng = (n >> 5) & 1, n32 = n & 31;
    const float* wp = w + (size_t)(ch * 16 + oct * 8) * N_TOT + n;

    u32 hp[4], lp[4];
#pragma unroll
    for (int e2 = 0; e2 < 4; ++e2) {
      const int e = e2 * 2;
      const float w0 = wp[(size_t)e * N_TOT];
      const float w1 = wp[(size_t)(e + 1) * N_TOT];
      const u32 t0 = tabW[(oct * 8 + e) * 16 + (int)(w0 + 8.0f)];
      const u32 t1 = tabW[(oct * 8 + e + 1) * 16 + (int)(w1 + 8.0f)];
      hp[e2] = pk_lo(t0, t1);
      lp[e2] = pk_hi(t0, t1);
    }
    // chunk base (u16): (nblk*64+ch)*2048 ; layout hl*1024 + ng*512 + oct*256 + n32*8
    const size_t wb = (size_t)(nblk * 64 + ch) * 2048 + ng * 512 + oct * 256 + n32 * 8;
    *(uint4*)&WHL[wb]        = make_uint4(hp[0], hp[1], hp[2], hp[3]);
    *(uint4*)&WHL[wb + 1024] = make_uint4(lp[0], lp[1], lp[2], lp[3]);
  }

  // ---- X presplit: block = (mblk, chunk-group of 4) ----
  {
    const int mblk = b >> 4, chg = b & 15;
    const int ml = tid >> 2, chl = tid & 3;
    const int rg = ml >> 5, row = ml & 31;
    const float4* xp4 = (const float4*)(x + (size_t)(mblk * 64 + ml) * K_TOT + (chg * 4 + chl) * 16);
    float4 v4[4] = { xp4[0], xp4[1], xp4[2], xp4[3] };
    const float* v = (const float*)v4;

    u32 hp[8], lp[8];
#pragma unroll
    for (int e2 = 0; e2 < 8; ++e2) {
      const int e = e2 * 2;
      const u32 t0 = tabX[e * 16 + (int)(v[e] + 8.0f)];
      const u32 t1 = tabX[(e + 1) * 16 + (int)(v[e + 1] + 8.0f)];
      hp[e2] = pk_lo(t0, t1);
      lp[e2] = pk_hi(t0, t1);
    }

    // LDS image in exact global layout: chl*4096 + hl*2048 + rg*1024 + oct*512 + row*16
    char* basep = lds + chl * 4096 + rg * 1024 + row * 16;
    *(uint4*)(basep)        = make_uint4(hp[0], hp[1], hp[2], hp[3]);  // h oct0
    *(uint4*)(basep + 512)  = make_uint4(hp[4], hp[5], hp[6], hp[7]);  // h oct1
    *(uint4*)(basep + 2048) = make_uint4(lp[0], lp[1], lp[2], lp[3]);  // l oct0
    *(uint4*)(basep + 2560) = make_uint4(lp[4], lp[5], lp[6], lp[7]);  // l oct1
    __syncthreads();

    // coalesced dump: 16KB contiguous (4 chunk-planes)
    const size_t gb = (size_t)(mblk * 64 + chg * 4) * 4096;  // bytes
    const int off = tid * 16;
    *(uint4*)((char*)XHL + gb + off)         = *(const uint4*)(lds + off);
    *(uint4*)((char*)XHL + gb + off + 4096)  = *(const uint4*)(lds + off + 4096);
    *(uint4*)((char*)XHL + gb + off + 8192)  = *(const uint4*)(lds + off + 8192);
    *(uint4*)((char*)XHL + gb + off + 12288) = *(const uint4*)(lds + off + 12288);
  }
}

__global__ __launch_bounds__(512, 4) void opu_main(
    const u16* __restrict__ XHL, const u16* __restrict__ WHL,
    float* __restrict__ out)
{
  __shared__ float cb[64 * 64];   // 16KB combine buffer

  const int tid  = threadIdx.x;
  const int wave = tid >> 6;      // 0..7 = (kh, mt, nt)
  const int lane = tid & 63;
  const int oct  = lane >> 5;
  const int ll   = lane & 31;
  const int kh   = wave >> 2;     // k-half: chunks [kh*32, kh*32+32)
  const int mt   = (wave >> 1) & 1;
  const int nt   = wave & 1;

  const int bx   = blockIdx.x;
  const int nblk = (bx & 1) + 2 * ((bx >> 3) & 7);   // 0..15  per-XCD swizzle
  const int mblk = ((bx >> 1) & 3) + 4 * (bx >> 6);  // 0..31

  // chunk page (u16): 2048 = [hl:1024][rg|ng:512]; lane*8 covers oct(512=lane>>5*256?
  // no: lane*8 u16 spans oct+row, matching fragment layout as in R17/R18).
  const u16* pA = XHL + (size_t)mblk * 131072 + (size_t)(kh * 32) * 2048 + mt * 512 + lane * 8;
  const u16* pB = WHL + (size_t)nblk * 131072 + (size_t)(kh * 32) * 2048 + nt * 512 + lane * 8;

  uint4 c0[4], c1[4], c2[4], c3[4];  // literal-indexed only (R7 lesson: ring idx -> scratch)

#define LQ(dst, ch)                                        \
  do {                                                     \
    const size_t o = (size_t)(ch) * 2048;                  \
    (dst)[0] = *(const uint4*)(pA + o);                    \
    (dst)[1] = *(const uint4*)(pA + o + 1024);             \
    (dst)[2] = *(const uint4*)(pB + o);                    \
    (dst)[3] = *(const uint4*)(pB + o + 1024);             \
  } while (0)

  float res[16];
#pragma unroll
  for (int i = 0; i < 16; ++i) res[i] = RBIAS;  // biased: each add RNE-rounds to int grid
  const f32x16 fzero = {};

  // Per chunk: 3-MFMA chain (AlBl dropped) then biased res += acc = per-chunk ADC rint.
#define CQ(c)                                                                     \
  do {                                                                            \
    const f16x8 Ah = __builtin_bit_cast(f16x8, (c)[0]);                           \
    const f16x8 Al = __builtin_bit_cast(f16x8, (c)[1]);                           \
    const f16x8 Bh = __builtin_bit_cast(f16x8, (c)[2]);                           \
    const f16x8 Bl = __builtin_bit_cast(f16x8, (c)[3]);                           \
    f32x16 a = __builtin_amdgcn_mfma_f32_32x32x16_f16(Ah, Bh, fzero, 0, 0, 0);    \
    a = __builtin_amdgcn_mfma_f32_32x32x16_f16(Al, Bh, a, 0, 0, 0);               \
    a = __builtin_amdgcn_mfma_f32_32x32x16_f16(Ah, Bl, a, 0, 0, 0);               \
    _Pragma("unroll")                                                             \
    for (int i = 0; i < 16; ++i) res[i] += a[i];                                  \
  } while (0)

#define CLAMP31(v) ((v) > 31 ? 31 : (v))

  // 3-deep prefetch, 4-buffer literal rotation (R18 pattern, proven correct: each of
  // the 32 chunks consumed exactly once; tail prefetches redundantly reload ch 31
  // but are never consumed).
  LQ(c0, 0); LQ(c1, 1); LQ(c2, 2);
#pragma unroll 1
  for (int it = 0; it < 8; ++it) {
    const int ch = it * 4;
    LQ(c3, ch + 3);            CQ(c0);
    LQ(c0, CLAMP31(ch + 4));   CQ(c1);
    LQ(c1, CLAMP31(ch + 5));   CQ(c2);
    LQ(c2, CLAMP31(ch + 6));   CQ(c3);
  }

  // ---- 2-step combine: kh=0 waves write their quadrant, kh=1 waves add (exact ints) ----
#define CBI(i) ((mt * 32 + ((i & 3) + 8 * (i >> 2) + 4 * oct)) * 64 + nt * 32 + ll)
  if (kh == 0) {
#pragma unroll
    for (int i = 0; i < 16; ++i) cb[CBI(i)] = res[i] - RBIAS;
  }
  __syncthreads();
  if (kh == 1) {
#pragma unroll
    for (int i = 0; i < 16; ++i) cb[CBI(i)] += res[i] - RBIAS;
  }
  __syncthreads();

  // ---- cooperative store: 512 threads x 8 floats ----
  const float4* cbv = (const float4*)cb;
  const int row = tid >> 3, c8 = tid & 7;
  float* orow = out + (size_t)(mblk * 64 + row) * N_TOT + nblk * 64 + c8 * 8;
#pragma unroll
  for (int p = 0; p < 2; ++p) {
    float4 v = cbv[row * 16 + c8 * 2 + p];
    v.x *= 16.0f; v.y *= 16.0f; v.z *= 16.0f; v.w *= 16.0f;
    *(float4*)&orow[p * 4] = v;
  }
}

extern "C" void kernel_launch(void* const* d_in, const int* in_sizes, int n_in,
                              void* d_out, int out_size, void* d_ws, size_t ws_size,
                              hipStream_t stream)
{
  const float* input  = (const float*)d_in[0];
  const float* weight = (const float*)d_in[1];
  const float* vmap   = (const float*)d_in[2];
  const float* wmap   = (const float*)d_in[3];
  float* out = (float*)d_out;

  u16* XHL = (u16*)d_ws;                         // 8MB (4M u16)
  u16* WHL = XHL + 4 * 1024 * 1024;              // 4MB   (ws use: 12MB total)

  presplit<<<512, 256, 0, stream>>>(input, weight, vmap, wmap, XHL, WHL);

  opu_main<<<512, 512, 0, stream>>>(XHL, WHL, out);
}